// Round 5
// baseline (452.040 us; speedup 1.0000x reference)
//
#include <hip/hip_runtime.h>

#define N 8192
#define DIN 512
#define DOUT 256
#define ALPHA 0.2f
#define NEG_INF -9.0e15f

typedef __attribute__((ext_vector_type(8))) short bf16x8;
typedef __attribute__((ext_vector_type(4))) float f32x4;
typedef __attribute__((ext_vector_type(16))) float f32x16;
typedef __attribute__((ext_vector_type(4))) int   i32x4;

__device__ __forceinline__ unsigned f2bf_u(float f) {
    unsigned u = __builtin_bit_cast(unsigned, f);
    return (u + 0x7fffu + ((u >> 16) & 1u)) >> 16;   // RNE bf16
}
__device__ __forceinline__ unsigned pack2bf(float lo, float hi) {
    return f2bf_u(lo) | (f2bf_u(hi) << 16);
}
union U4BF8 { uint4 u; bf16x8 v; };

__device__ __forceinline__ void async_copy16(const ushort* g, ushort* l) {
    __builtin_amdgcn_global_load_lds(
        (const __attribute__((address_space(1))) unsigned*)g,
        (__attribute__((address_space(3))) unsigned*)l, 16, 0, 0);
}

// Kernel 0: W fp32 [512][256] -> WB bf16 in MFMA-B layout ((k>>3)*256+c)*8+(k&7).
__global__ __launch_bounds__(256) void wb_kernel(const float* __restrict__ W,
                                                 ushort* __restrict__ WB) {
    const int g = blockIdx.x * 256 + threadIdx.x;   // 64*256 = 16384
    const int c = g & 255, k8 = g >> 8;
    const float* wp = W + (size_t)(k8 * 8) * DOUT + c;
    U4BF8 o;
    o.u.x = pack2bf(wp[0 * DOUT], wp[1 * DOUT]);
    o.u.y = pack2bf(wp[2 * DOUT], wp[3 * DOUT]);
    o.u.z = pack2bf(wp[4 * DOUT], wp[5 * DOUT]);
    o.u.w = pack2bf(wp[6 * DOUT], wp[7 * DOUT]);
    *(uint4*)(WB + (size_t)g * 8) = o.u;
}

// Kernel 1: h = X@W + b via MFMA, split-K across 4 waves (unchanged from R0).
__global__ __launch_bounds__(256) void h_kernel(
        const float* __restrict__ X, const ushort* __restrict__ WB,
        const float* __restrict__ bvec, const float* __restrict__ a,
        ushort* __restrict__ hB, float* __restrict__ el, float* __restrict__ er)
{
    __shared__ float red[4][64][65];
    __shared__ float elr[2][4][16];
    const int t = threadIdx.x;
    const int w = t >> 6, l = t & 63, q = l >> 4, n = l & 15;
    const int i0 = blockIdx.x * 16;
    f32x4 acc[16];
    #pragma unroll
    for (int ct = 0; ct < 16; ++ct) acc[ct] = (f32x4){0.f, 0.f, 0.f, 0.f};
    const float* xp = X + (size_t)(i0 + n) * DIN + q * 8;

    #pragma unroll
    for (int ks = 0; ks < 4; ++ks) {
        const int k0 = w * 128 + ks * 32;
        const float4 x0 = *(const float4*)(xp + k0);
        const float4 x1 = *(const float4*)(xp + k0 + 4);
        U4BF8 pa;
        pa.u.x = pack2bf(x0.x, x0.y); pa.u.y = pack2bf(x0.z, x0.w);
        pa.u.z = pack2bf(x1.x, x1.y); pa.u.w = pack2bf(x1.z, x1.w);
        const ushort* wbp = WB + ((k0 >> 3) + q) * 2048 + n * 8;
        bf16x8 bfr[16];
        #pragma unroll
        for (int ct = 0; ct < 16; ++ct) bfr[ct] = *(const bf16x8*)(wbp + ct * 128);
        #pragma unroll
        for (int ct = 0; ct < 16; ++ct)
            acc[ct] = __builtin_amdgcn_mfma_f32_16x16x32_bf16(pa.v, bfr[ct], acc[ct], 0, 0, 0);
    }
    #pragma unroll
    for (int ct = 0; ct < 16; ++ct)
        #pragma unroll
        for (int r = 0; r < 4; ++r) red[w][l][ct * 4 + r] = acc[ct][r];
    __syncthreads();

    float pl[4] = {0.f, 0.f, 0.f, 0.f}, pr[4] = {0.f, 0.f, 0.f, 0.f};
    const int hbase = (blockIdx.x * 2 + (q >> 1)) * 2048 + n * 8 + (q & 1) * 4;
    #pragma unroll
    for (int c2 = 0; c2 < 4; ++c2) {
        const int ct = w * 4 + c2;
        const float bb = bvec[ct * 16 + n];
        const float al = a[ct * 16 + n];
        const float ar = a[DOUT + ct * 16 + n];
        float v[4];
        #pragma unroll
        for (int r = 0; r < 4; ++r) {
            v[r] = red[0][l][ct * 4 + r] + red[1][l][ct * 4 + r]
                 + red[2][l][ct * 4 + r] + red[3][l][ct * 4 + r] + bb;
            pl[r] += v[r] * al;
            pr[r] += v[r] * ar;
        }
        ushort4 hp;
        hp.x = (ushort)f2bf_u(v[0]); hp.y = (ushort)f2bf_u(v[1]);
        hp.z = (ushort)f2bf_u(v[2]); hp.w = (ushort)f2bf_u(v[3]);
        *(ushort4*)&hB[hbase + ct * 128] = hp;
    }
    #pragma unroll
    for (int r = 0; r < 4; ++r) {
        #pragma unroll
        for (int off = 1; off < 16; off <<= 1) {
            pl[r] += __shfl_xor(pl[r], off);
            pr[r] += __shfl_xor(pr[r], off);
        }
    }
    if (n == 0) {
        #pragma unroll
        for (int r = 0; r < 4; ++r) {
            elr[0][w][q * 4 + r] = pl[r];
            elr[1][w][q * 4 + r] = pr[r];
        }
    }
    __syncthreads();
    if (t < 16) {
        el[i0 + t] = elr[0][0][t] + elr[0][1][t] + elr[0][2][t] + elr[0][3][t];
        er[i0 + t] = elr[1][0][t] + elr[1][1][t] + elr[1][2][t] + elr[1][3][t];
    }
}

// 8 masked-exp lanes -> one packed A-fragment word-group + running sum.
#define EXP8(ELM, E0, E1, M0, M1, PA, LS)                                          \
    {                                                                              \
        float v, p0, p1, p2, p3, p4, p5, p6, p7;                                   \
        v = ELM + E0.x; v = fmaxf(v, ALPHA * v); p0 = __expf(M0.x > 0 ? v : NEG_INF); \
        v = ELM + E0.y; v = fmaxf(v, ALPHA * v); p1 = __expf(M0.y > 0 ? v : NEG_INF); \
        v = ELM + E0.z; v = fmaxf(v, ALPHA * v); p2 = __expf(M0.z > 0 ? v : NEG_INF); \
        v = ELM + E0.w; v = fmaxf(v, ALPHA * v); p3 = __expf(M0.w > 0 ? v : NEG_INF); \
        v = ELM + E1.x; v = fmaxf(v, ALPHA * v); p4 = __expf(M1.x > 0 ? v : NEG_INF); \
        v = ELM + E1.y; v = fmaxf(v, ALPHA * v); p5 = __expf(M1.y > 0 ? v : NEG_INF); \
        v = ELM + E1.z; v = fmaxf(v, ALPHA * v); p6 = __expf(M1.z > 0 ? v : NEG_INF); \
        v = ELM + E1.w; v = fmaxf(v, ALPHA * v); p7 = __expf(M1.w > 0 ? v : NEG_INF); \
        LS += p0 + p1 + p2 + p3 + p4 + p5 + p6 + p7;                               \
        PA.u.x = pack2bf(p0, p1); PA.u.y = pack2bf(p2, p3);                        \
        PA.u.z = pack2bf(p4, p5); PA.u.w = pack2bf(p6, p7);                        \
    }

// Kernel 2 (v6): R0 skeleton (512 thr, 128 rows x j-quarter, 16 steps of 128 j,
// double-buffered 64 KB stage, plain __syncthreads) with ONE change: 32x32x16
// MFMA, ct-split. Wave w: row-group rg=w>>1 (32 rows), col-half ch=w&1 (128 c).
// B-frag reads halve (32 vs 64 ds_read_b128/wave/step); acc = 64 VGPR; no
// split-K epilogue. exp/adj work duplicated across the ch-pair (VALU-cheap,
// adj lines L1-hit for the sibling wave -> cached loads, not nontemporal).
__global__ __launch_bounds__(512, 2) void attn_kernel(
        const int* __restrict__ adj, const float* __restrict__ el,
        const float* __restrict__ er, const float* __restrict__ ab,
        const ushort* __restrict__ hB, float* __restrict__ pout,
        float* __restrict__ plsum)
{
    __shared__ ushort stage[2][32768];   // 2 x 64 KB (128 j x 256 c bf16)
    __shared__ float ers[2048];          // 8 KB
    const int t = threadIdx.x;
    const int w = t >> 6, l = t & 63;
    const int rg = w >> 1, ch = w & 1;   // row-group (32 rows), col-half (128 c)
    const int r32 = l & 31, hi = l >> 5;
    const int rb = blockIdx.x >> 2, jq = blockIdx.x & 3;
    const int j0 = jq * 2048;
    const int row = rb * 128 + rg * 32 + r32;
    const float elm = el[row] + ab[0];
    const int* alp = adj + (size_t)row * N + j0 + hi * 8;

    f32x16 acc[4];
    #pragma unroll
    for (int ct = 0; ct < 4; ++ct)
        #pragma unroll
        for (int r = 0; r < 16; ++r) acc[ct][r] = 0.f;
    float lsum = 0.f;

    // prologue: er quarter -> LDS; adj regs for step 0; hB step-0 tile -> stage[0]
    *(float4*)&ers[t * 4] = *(const float4*)&er[j0 + t * 4];
    i32x4 adjA[8], adjB[8];
    #pragma unroll
    for (int ks = 0; ks < 4; ++ks) {
        adjA[2 * ks]     = *(const i32x4*)(alp + ks * 16);
        adjA[2 * ks + 1] = *(const i32x4*)(alp + ks * 16 + 4);
        adjB[2 * ks]     = *(const i32x4*)(alp + 64 + ks * 16);
        adjB[2 * ks + 1] = *(const i32x4*)(alp + 64 + ks * 16 + 4);
    }
    {
        const ushort* g = hB + (size_t)j0 * 256 + t * 8;
        ushort* lb = &stage[0][t * 8];
        #pragma unroll
        for (int i = 0; i < 8; ++i) async_copy16(g + i * 4096, lb + i * 4096);
    }

    for (int s = 0; s < 16; ++s) {
        __syncthreads();                 // stage[s&1] + ers + adj regs ready
        if (s < 15) {                    // next hB tile (runs in background)
            const ushort* g = hB + (size_t)(j0 + (s + 1) * 128) * 256 + t * 8;
            ushort* lb = &stage[(s + 1) & 1][t * 8];
            #pragma unroll
            for (int i = 0; i < 8; ++i) async_copy16(g + i * 4096, lb + i * 4096);
        }
        const ushort* sbase = &stage[s & 1][ch * 1024 + r32 * 8];
        // half 0: k-slices 0..3 (j = s*128 + ks*16 + hi*8 + 0..7)
        #pragma unroll
        for (int ks = 0; ks < 4; ++ks) {
            const float4 e0 = *(const float4*)&ers[s * 128 + ks * 16 + hi * 8];
            const float4 e1 = *(const float4*)&ers[s * 128 + ks * 16 + hi * 8 + 4];
            U4BF8 pa;
            EXP8(elm, e0, e1, adjA[2 * ks], adjA[2 * ks + 1], pa, lsum);
            const ushort* sb = sbase + (ks * 2 + hi) * 2048;
            #pragma unroll
            for (int ct = 0; ct < 4; ++ct) {
                const bf16x8 bf = *(const bf16x8*)(sb + ct * 256);
                acc[ct] = __builtin_amdgcn_mfma_f32_32x32x16_bf16(pa.v, bf, acc[ct], 0, 0, 0);
            }
        }
        if (s < 15) {                    // refill adjA for step s+1
            const int* ap = alp + (s + 1) * 128;
            #pragma unroll
            for (int ks = 0; ks < 4; ++ks) {
                adjA[2 * ks]     = *(const i32x4*)(ap + ks * 16);
                adjA[2 * ks + 1] = *(const i32x4*)(ap + ks * 16 + 4);
            }
        }
        // half 1: k-slices 4..7 (j = s*128 + 64 + ks*16 + hi*8 + 0..7)
        #pragma unroll
        for (int ks = 0; ks < 4; ++ks) {
            const float4 e0 = *(const float4*)&ers[s * 128 + 64 + ks * 16 + hi * 8];
            const float4 e1 = *(const float4*)&ers[s * 128 + 64 + ks * 16 + hi * 8 + 4];
            U4BF8 pa;
            EXP8(elm, e0, e1, adjB[2 * ks], adjB[2 * ks + 1], pa, lsum);
            const ushort* sb = sbase + (8 + ks * 2 + hi) * 2048;
            #pragma unroll
            for (int ct = 0; ct < 4; ++ct) {
                const bf16x8 bf = *(const bf16x8*)(sb + ct * 256);
                acc[ct] = __builtin_amdgcn_mfma_f32_32x32x16_bf16(pa.v, bf, acc[ct], 0, 0, 0);
            }
        }
        if (s < 15) {                    // refill adjB for step s+1
            const int* ap = alp + (s + 1) * 128 + 64;
            #pragma unroll
            for (int ks = 0; ks < 4; ++ks) {
                adjB[2 * ks]     = *(const i32x4*)(ap + ks * 16);
                adjB[2 * ks + 1] = *(const i32x4*)(ap + ks * 16 + 4);
            }
        }
    }

    // row sums: lanes l and l^32 hold complementary j-sets of the same row.
    lsum += __shfl_xor(lsum, 32);
    if (ch == 0 && l < 32)
        plsum[(size_t)jq * N + rb * 128 + rg * 32 + l] = lsum;

    // unnormalized partial tile. C/D 32x32: col = ct*32 + r32 (+ch*128),
    // row = (r&3) + 8*(r>>2) + 4*hi  (verified mapping).
    float* pb = pout + ((size_t)jq * N + rb * 128 + rg * 32) * 256 + ch * 128 + r32;
    #pragma unroll
    for (int ct = 0; ct < 4; ++ct)
        #pragma unroll
        for (int r = 0; r < 16; ++r) {
            const int rl = (r & 3) + 8 * (r >> 2) + 4 * hi;
            __builtin_nontemporal_store(acc[ct][r], pb + (size_t)rl * 256 + ct * 32);
        }
}

// Kernel 3: combine j-quarter partials + normalize. grid 2048 x 256.
__global__ __launch_bounds__(256) void combine_kernel(
        const float* __restrict__ pout, const float* __restrict__ plsum,
        float* __restrict__ out)
{
    const int t = threadIdx.x;
    const int row = blockIdx.x * 4 + (t >> 6);
    const int c = (t & 63) * 4;
    const size_t idx = (size_t)row * 256 + c;
    const size_t qs = (size_t)N * 256;
    float4 v0 = *(const float4*)&pout[idx];
    float4 v1 = *(const float4*)&pout[idx + qs];
    float4 v2 = *(const float4*)&pout[idx + 2 * qs];
    float4 v3 = *(const float4*)&pout[idx + 3 * qs];
    const float li = 1.0f / (plsum[row] + plsum[N + row]
                           + plsum[2 * N + row] + plsum[3 * N + row]);
    float4 o;
    o.x = (v0.x + v1.x + v2.x + v3.x) * li;
    o.y = (v0.y + v1.y + v2.y + v3.y) * li;
    o.z = (v0.z + v1.z + v2.z + v3.z) * li;
    o.w = (v0.w + v1.w + v2.w + v3.w) * li;
    *(float4*)&out[idx] = o;
}

extern "C" void kernel_launch(void* const* d_in, const int* in_sizes, int n_in,
                              void* d_out, int out_size, void* d_ws, size_t ws_size,
                              hipStream_t stream) {
    const int*   adj = (const int*)  d_in[0];
    const float* X   = (const float*)d_in[1];
    const float* W   = (const float*)d_in[2];
    const float* b   = (const float*)d_in[3];
    const float* a   = (const float*)d_in[4];
    const float* ab  = (const float*)d_in[5];
    float* out = (float*)d_out;

    ushort* hB    = (ushort*)d_ws;                        // 4 MB
    ushort* WB    = hB + (size_t)N * DOUT;                // 256 KB
    float*  el    = (float*)(WB + (size_t)DIN * DOUT);    // 32 KB
    float*  er    = el + N;                               // 32 KB
    float*  plsum = er + N;                               // 4*N fp32 = 128 KB
    float*  pout  = plsum + 4 * N;                        // 4*N*256 fp32 = 32 MB

    wb_kernel<<<dim3(64), dim3(256), 0, stream>>>(W, WB);
    h_kernel<<<dim3(N / 16), dim3(256), 0, stream>>>(X, WB, b, a, hB, el, er);
    attn_kernel<<<dim3(256), dim3(512), 0, stream>>>(adj, el, er, ab, hB, pout, plsum);
    combine_kernel<<<dim3(N / 4), dim3(256), 0, stream>>>(pout, plsum, out);
}

// Round 6
// 441.590 us; speedup vs baseline: 1.0237x; 1.0237x over previous
//
#include <hip/hip_runtime.h>

#define N 8192
#define DIN 512
#define DOUT 256
#define ALPHA 0.2f
#define NEG_INF -9.0e15f

typedef __attribute__((ext_vector_type(8))) short bf16x8;
typedef __attribute__((ext_vector_type(4))) float f32x4;
typedef __attribute__((ext_vector_type(4))) int   i32x4;

__device__ __forceinline__ unsigned f2bf_u(float f) {
    unsigned u = __builtin_bit_cast(unsigned, f);
    return (u + 0x7fffu + ((u >> 16) & 1u)) >> 16;   // RNE bf16
}
__device__ __forceinline__ unsigned pack2bf(float lo, float hi) {
    return f2bf_u(lo) | (f2bf_u(hi) << 16);
}
union U4BF8 { uint4 u; bf16x8 v; };

__device__ __forceinline__ void async_copy16(const ushort* g, ushort* l) {
    __builtin_amdgcn_global_load_lds(
        (const __attribute__((address_space(1))) unsigned*)g,
        (__attribute__((address_space(3))) unsigned*)l, 16, 0, 0);
}

// Kernel 0: W fp32 [512][256] -> WB bf16 in MFMA-B layout ((k>>3)*256+c)*8+(k&7).
__global__ __launch_bounds__(256) void wb_kernel(const float* __restrict__ W,
                                                 ushort* __restrict__ WB) {
    const int g = blockIdx.x * 256 + threadIdx.x;   // 64*256 = 16384
    const int c = g & 255, k8 = g >> 8;
    const float* wp = W + (size_t)(k8 * 8) * DOUT + c;
    U4BF8 o;
    o.u.x = pack2bf(wp[0 * DOUT], wp[1 * DOUT]);
    o.u.y = pack2bf(wp[2 * DOUT], wp[3 * DOUT]);
    o.u.z = pack2bf(wp[4 * DOUT], wp[5 * DOUT]);
    o.u.w = pack2bf(wp[6 * DOUT], wp[7 * DOUT]);
    *(uint4*)(WB + (size_t)g * 8) = o.u;
}

// Kernel 1: h = X@W + b via MFMA, split-K across 4 waves (unchanged from R0).
__global__ __launch_bounds__(256) void h_kernel(
        const float* __restrict__ X, const ushort* __restrict__ WB,
        const float* __restrict__ bvec, const float* __restrict__ a,
        ushort* __restrict__ hB, float* __restrict__ el, float* __restrict__ er)
{
    __shared__ float red[4][64][65];
    __shared__ float elr[2][4][16];
    const int t = threadIdx.x;
    const int w = t >> 6, l = t & 63, q = l >> 4, n = l & 15;
    const int i0 = blockIdx.x * 16;
    f32x4 acc[16];
    #pragma unroll
    for (int ct = 0; ct < 16; ++ct) acc[ct] = (f32x4){0.f, 0.f, 0.f, 0.f};
    const float* xp = X + (size_t)(i0 + n) * DIN + q * 8;

    #pragma unroll
    for (int ks = 0; ks < 4; ++ks) {
        const int k0 = w * 128 + ks * 32;
        const float4 x0 = *(const float4*)(xp + k0);
        const float4 x1 = *(const float4*)(xp + k0 + 4);
        U4BF8 pa;
        pa.u.x = pack2bf(x0.x, x0.y); pa.u.y = pack2bf(x0.z, x0.w);
        pa.u.z = pack2bf(x1.x, x1.y); pa.u.w = pack2bf(x1.z, x1.w);
        const ushort* wbp = WB + ((k0 >> 3) + q) * 2048 + n * 8;
        bf16x8 bfr[16];
        #pragma unroll
        for (int ct = 0; ct < 16; ++ct) bfr[ct] = *(const bf16x8*)(wbp + ct * 128);
        #pragma unroll
        for (int ct = 0; ct < 16; ++ct)
            acc[ct] = __builtin_amdgcn_mfma_f32_16x16x32_bf16(pa.v, bfr[ct], acc[ct], 0, 0, 0);
    }
    #pragma unroll
    for (int ct = 0; ct < 16; ++ct)
        #pragma unroll
        for (int r = 0; r < 4; ++r) red[w][l][ct * 4 + r] = acc[ct][r];
    __syncthreads();

    float pl[4] = {0.f, 0.f, 0.f, 0.f}, pr[4] = {0.f, 0.f, 0.f, 0.f};
    const int hbase = (blockIdx.x * 2 + (q >> 1)) * 2048 + n * 8 + (q & 1) * 4;
    #pragma unroll
    for (int c2 = 0; c2 < 4; ++c2) {
        const int ct = w * 4 + c2;
        const float bb = bvec[ct * 16 + n];
        const float al = a[ct * 16 + n];
        const float ar = a[DOUT + ct * 16 + n];
        float v[4];
        #pragma unroll
        for (int r = 0; r < 4; ++r) {
            v[r] = red[0][l][ct * 4 + r] + red[1][l][ct * 4 + r]
                 + red[2][l][ct * 4 + r] + red[3][l][ct * 4 + r] + bb;
            pl[r] += v[r] * al;
            pr[r] += v[r] * ar;
        }
        ushort4 hp;
        hp.x = (ushort)f2bf_u(v[0]); hp.y = (ushort)f2bf_u(v[1]);
        hp.z = (ushort)f2bf_u(v[2]); hp.w = (ushort)f2bf_u(v[3]);
        *(ushort4*)&hB[hbase + ct * 128] = hp;
    }
    #pragma unroll
    for (int r = 0; r < 4; ++r) {
        #pragma unroll
        for (int off = 1; off < 16; off <<= 1) {
            pl[r] += __shfl_xor(pl[r], off);
            pr[r] += __shfl_xor(pr[r], off);
        }
    }
    if (n == 0) {
        #pragma unroll
        for (int r = 0; r < 4; ++r) {
            elr[0][w][q * 4 + r] = pl[r];
            elr[1][w][q * 4 + r] = pr[r];
        }
    }
    __syncthreads();
    if (t < 16) {
        el[i0 + t] = elr[0][0][t] + elr[0][1][t] + elr[0][2][t] + elr[0][3][t];
        er[i0 + t] = elr[1][0][t] + elr[1][1][t] + elr[1][2][t] + elr[1][3][t];
    }
}

// 8 masked-exp lanes -> one packed A-fragment word-group + running sum.
#define EXP8(ELM, E0, E1, M0, M1, PA, LS)                                          \
    {                                                                              \
        float v, p0, p1, p2, p3, p4, p5, p6, p7;                                   \
        v = ELM + E0.x; v = fmaxf(v, ALPHA * v); p0 = __expf(M0.x > 0 ? v : NEG_INF); \
        v = ELM + E0.y; v = fmaxf(v, ALPHA * v); p1 = __expf(M0.y > 0 ? v : NEG_INF); \
        v = ELM + E0.z; v = fmaxf(v, ALPHA * v); p2 = __expf(M0.z > 0 ? v : NEG_INF); \
        v = ELM + E0.w; v = fmaxf(v, ALPHA * v); p3 = __expf(M0.w > 0 ? v : NEG_INF); \
        v = ELM + E1.x; v = fmaxf(v, ALPHA * v); p4 = __expf(M1.x > 0 ? v : NEG_INF); \
        v = ELM + E1.y; v = fmaxf(v, ALPHA * v); p5 = __expf(M1.y > 0 ? v : NEG_INF); \
        v = ELM + E1.z; v = fmaxf(v, ALPHA * v); p6 = __expf(M1.z > 0 ? v : NEG_INF); \
        v = ELM + E1.w; v = fmaxf(v, ALPHA * v); p7 = __expf(M1.w > 0 ? v : NEG_INF); \
        LS += p0 + p1 + p2 + p3 + p4 + p5 + p6 + p7;                               \
        PA.u.x = pack2bf(p0, p1); PA.u.y = pack2bf(p2, p3);                        \
        PA.u.z = pack2bf(p4, p5); PA.u.w = pack2bf(p6, p7);                        \
    }

// Kernel 2 (v7): R0 compute structure (16x16x32 MFMA, wave = 16 rows, q =
// k-offset), but grid = 64 row-blocks x 8 j-eighths = 512 blocks -> TWO
// independent blocks (barrier domains) per CU. Steps of 64 j (16 steps of
// 1024 j); stage 2 x 32 KB + ers 4 KB = 68 KB/block -> 136 KB/CU. When one
// block drains at its barrier, the other block's 8 waves keep the pipes
// busy (counters showed 65% stall at 1 block/CU, nothing saturated).
__global__ __launch_bounds__(512, 4) void attn_kernel(
        const int* __restrict__ adj, const float* __restrict__ el,
        const float* __restrict__ er, const float* __restrict__ ab,
        const ushort* __restrict__ hB, float* __restrict__ pout,
        float* __restrict__ plsum)
{
    __shared__ ushort stage[2][16384];   // 2 x 32 KB (64 j x 256 c bf16)
    __shared__ float ers[1024];          // 4 KB
    const int t = threadIdx.x;
    const int w = t >> 6, l = t & 63, q = l >> 4, n = l & 15;
    const int rb = blockIdx.x >> 3, je = blockIdx.x & 7;
    const int j0 = je * 1024;
    const int row = rb * 128 + w * 16 + n;
    const float elm = el[row] + ab[0];
    const int* alp = adj + (size_t)row * N + j0 + q * 8;

    f32x4 acc[16];
    #pragma unroll
    for (int ct = 0; ct < 16; ++ct) acc[ct] = (f32x4){0.f, 0.f, 0.f, 0.f};
    float lsum = 0.f;

    // prologue: er eighth -> LDS; adj regs for step 0; hB step-0 tile -> stage[0]
    if (t < 256) *(float4*)&ers[t * 4] = *(const float4*)&er[j0 + t * 4];
    i32x4 a[4];
    #pragma unroll
    for (int kg = 0; kg < 2; ++kg) {
        a[2 * kg]     = *(const i32x4*)(alp + kg * 32);
        a[2 * kg + 1] = *(const i32x4*)(alp + kg * 32 + 4);
    }
    {
        const ushort* g = hB + (size_t)j0 * 256 + t * 8;
        ushort* lb = &stage[0][t * 8];
        #pragma unroll
        for (int i = 0; i < 4; ++i) async_copy16(g + i * 4096, lb + i * 4096);
    }

    for (int s = 0; s < 16; ++s) {
        __syncthreads();                 // stage[s&1] + ers + adj regs ready
        if (s < 15) {                    // next hB tile (flies during this step)
            const ushort* g = hB + (size_t)(j0 + (s + 1) * 64) * 256 + t * 8;
            ushort* lb = &stage[(s + 1) & 1][t * 8];
            #pragma unroll
            for (int i = 0; i < 4; ++i) async_copy16(g + i * 4096, lb + i * 4096);
        }
        // A-fragments: 2 K-groups of 32 j; lane (q,n): j = kg*32 + q*8 + 0..7
        U4BF8 pa[2];
        #pragma unroll
        for (int kg = 0; kg < 2; ++kg) {
            const float4 e0 = *(const float4*)&ers[s * 64 + kg * 32 + q * 8];
            const float4 e1 = *(const float4*)&ers[s * 64 + kg * 32 + q * 8 + 4];
            EXP8(elm, e0, e1, a[2 * kg], a[2 * kg + 1], pa[kg], lsum);
        }
        if (s < 15) {                    // adj regs for step s+1 (ride the barrier)
            const int* ap = alp + (s + 1) * 64;
            #pragma unroll
            for (int kg = 0; kg < 2; ++kg) {
                a[2 * kg]     = *(const i32x4*)(ap + kg * 32);
                a[2 * kg + 1] = *(const i32x4*)(ap + kg * 32 + 4);
            }
        }
        #pragma unroll
        for (int kg = 0; kg < 2; ++kg) {
            const ushort* sb = &stage[s & 1][(kg * 4 + q) * 2048 + n * 8];
            #pragma unroll
            for (int ct = 0; ct < 16; ++ct) {
                const bf16x8 bf = *(const bf16x8*)(sb + ct * 128);
                acc[ct] = __builtin_amdgcn_mfma_f32_16x16x32_bf16(pa[kg].v, bf, acc[ct], 0, 0, 0);
            }
        }
    }

    // row sums: the 4 q-groups of each half-wave hold the same row n
    lsum += __shfl_xor(lsum, 16);
    lsum += __shfl_xor(lsum, 32);
    if (l < 16) plsum[(size_t)je * N + row] = lsum;

    // unnormalized partial tile: row rb*128 + w*16 + q*4 + r, col ct*16 + n
    float* pb = pout + ((size_t)je * N + rb * 128 + w * 16 + q * 4) * 256 + n;
    #pragma unroll
    for (int ct = 0; ct < 16; ++ct)
        #pragma unroll
        for (int r = 0; r < 4; ++r)
            __builtin_nontemporal_store(acc[ct][r], pb + (size_t)r * 256 + ct * 16);
}

// Kernel 3: combine 8 j-eighth partials + normalize. grid 2048 x 256.
__global__ __launch_bounds__(256) void combine_kernel(
        const float* __restrict__ pout, const float* __restrict__ plsum,
        float* __restrict__ out)
{
    const int t = threadIdx.x;
    const int row = blockIdx.x * 4 + (t >> 6);
    const int c = (t & 63) * 4;
    const size_t idx = (size_t)row * 256 + c;
    const size_t qs = (size_t)N * 256;
    float4 acc = *(const float4*)&pout[idx];
    float ls = plsum[row];
    #pragma unroll
    for (int k = 1; k < 8; ++k) {
        const float4 v = *(const float4*)&pout[idx + k * qs];
        acc.x += v.x; acc.y += v.y; acc.z += v.z; acc.w += v.w;
        ls += plsum[k * N + row];
    }
    const float li = 1.0f / ls;
    float4 o;
    o.x = acc.x * li; o.y = acc.y * li; o.z = acc.z * li; o.w = acc.w * li;
    *(float4*)&out[idx] = o;
}

extern "C" void kernel_launch(void* const* d_in, const int* in_sizes, int n_in,
                              void* d_out, int out_size, void* d_ws, size_t ws_size,
                              hipStream_t stream) {
    const int*   adj = (const int*)  d_in[0];
    const float* X   = (const float*)d_in[1];
    const float* W   = (const float*)d_in[2];
    const float* b   = (const float*)d_in[3];
    const float* a   = (const float*)d_in[4];
    const float* ab  = (const float*)d_in[5];
    float* out = (float*)d_out;

    ushort* hB    = (ushort*)d_ws;                        // 4 MB
    ushort* WB    = hB + (size_t)N * DOUT;                // 256 KB
    float*  el    = (float*)(WB + (size_t)DIN * DOUT);    // 32 KB
    float*  er    = el + N;                               // 32 KB
    float*  plsum = er + N;                               // 8*N fp32 = 256 KB
    float*  pout  = plsum + 8 * N;                        // 8*N*256 fp32 = 64 MB

    wb_kernel<<<dim3(64), dim3(256), 0, stream>>>(W, WB);
    h_kernel<<<dim3(N / 16), dim3(256), 0, stream>>>(X, WB, b, a, hB, el, er);
    attn_kernel<<<dim3(512), dim3(512), 0, stream>>>(adj, el, er, ab, hB, pout, plsum);
    combine_kernel<<<dim3(N / 4), dim3(256), 0, stream>>>(pout, plsum, out);
}